// Round 8
// baseline (2351.577 us; speedup 1.0000x reference)
//
#include <hip/hip_runtime.h>

// Problem constants
#define BB   512
#define TT   128
#define DD   512
#define DS   256
#define UD   128
#define NO   40
#define G4   2048
#define KY   640
#define NY   48

#define NRG  8               // row groups (64 rows each)
#define NCS  32              // col slices (16 d-cols each)
#define NFLAGS (NRG*4*32)    // per-(group,wave) x 32 col-slices
// frag-major LDS: W0 [20 kc][4 lh][64 col][8 e], W1 [16 kc][4][64][8]
#define LDS_W0  (640*64*2)          // 81920
#define LDS_W1  (512*64*2)          // 65536
#define LDSB    (LDS_W0 + LDS_W1)   // 147456

typedef __bf16 bf16x8 __attribute__((ext_vector_type(8)));
typedef float  f32x4  __attribute__((ext_vector_type(4)));

__device__ __forceinline__ f32x4 mfma16(bf16x8 a, bf16x8 b, f32x4 c) {
  return __builtin_amdgcn_mfma_f32_16x16x32_bf16(a, b, c, 0, 0, 0);
}
__device__ __forceinline__ float sigm(float x)     { return 1.0f / (1.0f + __expf(-x)); }
__device__ __forceinline__ float tanhfast(float x) { return 2.0f / (1.0f + __expf(-2.0f * x)) - 1.0f; }

__device__ __forceinline__ bf16x8 cvt8(const float* __restrict__ p) {
  const float4 u0 = *reinterpret_cast<const float4*>(p);
  const float4 u1 = *reinterpret_cast<const float4*>(p + 4);
  bf16x8 r;
  r[0]=(__bf16)u0.x; r[1]=(__bf16)u0.y; r[2]=(__bf16)u0.z; r[3]=(__bf16)u0.w;
  r[4]=(__bf16)u1.x; r[5]=(__bf16)u1.y; r[6]=(__bf16)u1.z; r[7]=(__bf16)u1.w;
  return r;
}
__device__ __forceinline__ bf16x8 cvt8s(const float* __restrict__ p, float s) {
  const float4 u0 = *reinterpret_cast<const float4*>(p);
  const float4 u1 = *reinterpret_cast<const float4*>(p + 4);
  bf16x8 r;
  r[0]=(__bf16)(u0.x*s); r[1]=(__bf16)(u0.y*s); r[2]=(__bf16)(u0.z*s); r[3]=(__bf16)(u0.w*s);
  r[4]=(__bf16)(u1.x*s); r[5]=(__bf16)(u1.y*s); r[6]=(__bf16)(u1.z*s); r[7]=(__bf16)(u1.w*s);
  return r;
}
__device__ __forceinline__ bf16x8 pack2(float4 a, float4 b, float s) {
  bf16x8 r;
  r[0]=(__bf16)(a.x*s); r[1]=(__bf16)(a.y*s); r[2]=(__bf16)(a.z*s); r[3]=(__bf16)(a.w*s);
  r[4]=(__bf16)(b.x*s); r[5]=(__bf16)(b.y*s); r[6]=(__bf16)(b.z*s); r[7]=(__bf16)(b.w*s);
  return r;
}

// ---- proven primitives (R2/R5 semantics): agent-scope comms only ----------
#define LDIC16(dst, base, IMM)                                              \
  asm volatile("global_load_dwordx4 %0, %1, off offset:" #IMM " sc0 sc1"    \
               : "=&v"(dst) : "v"(base));
#define LDP16(dst, base, IMM)                                               \
  asm volatile("global_load_dwordx4 %0, %1, off offset:" #IMM               \
               : "=&v"(dst) : "v"(base));
#define WAITV0                                                              \
  { asm volatile("s_waitcnt vmcnt(0)" ::: "memory");                        \
    __builtin_amdgcn_sched_barrier(0); }

#define LOADH(base)                                                         \
  LDIC16(hh0, base, 0)    LDIC16(hh1, base, 64)                             \
  LDIC16(hh2, base, 128)  LDIC16(hh3, base, 192)                            \
  LDIC16(hh4, base, 256)  LDIC16(hh5, base, 320)                            \
  LDIC16(hh6, base, 384)  LDIC16(hh7, base, 448)                            \
  LDIC16(hh8, base, 512)  LDIC16(hh9, base, 576)                            \
  LDIC16(hhA, base, 640)  LDIC16(hhB, base, 704)                            \
  LDIC16(hhC, base, 768)  LDIC16(hhD, base, 832)                            \
  LDIC16(hhE, base, 896)  LDIC16(hhF, base, 960)

// agent-scope bf16 store (R2/R5-proven)
__device__ __forceinline__ void st_ic(__bf16* p, float v) {
  __bf16 h = (__bf16)v;
  unsigned short us = __builtin_bit_cast(unsigned short, h);
  __hip_atomic_store((unsigned short*)p, us, __ATOMIC_RELAXED, __HIP_MEMORY_SCOPE_AGENT);
}

// wave-plane poll: lanes 0-31 read 32 packed flags (2 cachelines), wave-uniform exit
__device__ __forceinline__ void wave_poll(int* fp, int ep, int lane, int& budget) {
  for (;;) {
    int fv = 0x7fffffff;
    if (lane < 32)
      fv = __hip_atomic_load(fp + lane, __ATOMIC_RELAXED, __HIP_MEMORY_SCOPE_AGENT);
    if (__all(fv >= ep)) break;
    if (--budget < 0) break;                 // hang guard
    __builtin_amdgcn_s_sleep(1);
  }
}

// ---------------- one-time prep ----------------
__global__ __launch_bounds__(256) void prep_kernel(
    const float* __restrict__ z_dyn,
    const float* __restrict__ Cw, const float* __restrict__ Dw,
    __bf16* __restrict__ CD, __bf16* __restrict__ hbuf, int* __restrict__ flags)
{
  int idx = blockIdx.x * 256 + threadIdx.x;
  if (idx < NFLAGS) flags[idx] = 0;
  if (idx < NY * KY) {
    int o = idx / KY, k = idx - o * KY;
    float v = 0.f;
    if (o < NO) v = (k < DD) ? Cw[o * DD + k] : Dw[o * UD + (k - DD)];
    CD[idx] = (__bf16)v;
  }
  if (idx < BB * DD) hbuf[idx] = (__bf16)z_dyn[idx];
}

// ---------------- U * dt -> bf16, one pass ----------------
__global__ __launch_bounds__(256) void ucvt_kernel(
    const float* __restrict__ U, const float* __restrict__ dtp,
    __bf16* __restrict__ Ubf)
{
  float dtv = dtp[0];
  size_t i = ((size_t)blockIdx.x * 256 + threadIdx.x) * 8;   // 8.39M total / 8
  float4 a = *reinterpret_cast<const float4*>(U + i);
  float4 b = *reinterpret_cast<const float4*>(U + i + 4);
  *reinterpret_cast<bf16x8*>(Ubf + i) = pack2(a, b, dtv);
}

// ---------------- pre0[b,j] = z_static @ Wih0[:,128:384]^T + bih0 + bhh0 ----
__global__ __launch_bounds__(256) void pre0_kernel(
    const float* __restrict__ z_static, const float* __restrict__ Wih0,
    const float* __restrict__ bih0, const float* __restrict__ bhh0,
    float* __restrict__ pre0)
{
  int lane = threadIdx.x & 63, w = threadIdx.x >> 6;
  int rm = lane & 15;
  int row = blockIdx.x * 64 + w * 16 + rm;
  int j0 = blockIdx.y * 64;
  int klane = (lane >> 4) * 8;
  f32x4 acc[4] = {};
  for (int k0 = 0; k0 < DS; k0 += 32) {
    int k = k0 + klane;
    bf16x8 a = cvt8(&z_static[row * DS + k]);
#pragma unroll
    for (int cf = 0; cf < 4; ++cf) {
      int j = j0 + cf * 16 + rm;
      bf16x8 b = cvt8(&Wih0[j * (UD + DS) + UD + k]);
      acc[cf] = mfma16(a, b, acc[cf]);
    }
  }
  int rbase = blockIdx.x * 64 + w * 16 + (lane >> 4) * 4;
#pragma unroll
  for (int cf = 0; cf < 4; ++cf) {
    int j = j0 + cf * 16 + rm;
    float bj = bih0[j] + bhh0[j];
#pragma unroll
    for (int q = 0; q < 4; ++q)
      pre0[(size_t)(rbase + q) * G4 + j] = acc[cf][q] + bj;
  }
}

// ---------------- persistent scan kernel ----------------
// 256 blocks x 256 threads, 1 block/CU. block (r=bid&7, c=bid>>3):
// rows [r*64,+64), d-cols [c*16,+16) x 4 gates. W0+W1 frag-major in LDS.
// Wave w syncs ONLY with wave-w counterparts across the 32 col-slices
// (it consumes exactly the rows they write) -> per-(r,w) flag plane of
// 32 packed ints; no __syncthreads in the loop.
template <bool UBF>
__global__ __launch_bounds__(256, 1) void persist_kernel(
    const float* __restrict__ U, const __bf16* __restrict__ Ubf,
    const float* __restrict__ dtp,
    const float* __restrict__ Wih0, const float* __restrict__ Whh0,
    const float* __restrict__ Wih1, const float* __restrict__ Whh1,
    const float* __restrict__ bih1, const float* __restrict__ bhh1,
    const float* __restrict__ pre0,
    __bf16* __restrict__ hbuf, __bf16* __restrict__ h1buf,
    int* __restrict__ flags, float* __restrict__ Z)
{
  extern __shared__ __align__(16) char smem[];
  __bf16* W0L = (__bf16*)smem;
  __bf16* W1L = (__bf16*)(smem + LDS_W0);

  const int tid = threadIdx.x;
  const int r = blockIdx.x & 7, c = blockIdx.x >> 3;
  const int c16 = c * 16;

  // stage W0 frag-major: (col,k) -> [((k>>5)*4+((k>>3)&3))*512 + col*8 + (k&7)]
  for (int idx = tid; idx < 64 * 640; idx += 256) {
    int col = idx / 640, k = idx - col * 640;
    int g = col >> 4, i = col & 15;
    size_t j = (size_t)(g * DD + c16 + i);
    float v = (k < UD) ? Wih0[j * (UD + DS) + k] : Whh0[j * DD + (k - UD)];
    W0L[((k >> 5) * 4 + ((k >> 3) & 3)) * 512 + col * 8 + (k & 7)] = (__bf16)v;
  }
  // stage W1 = Wih1+Whh1 frag-major
  for (int idx = tid; idx < 64 * 512; idx += 256) {
    int col = idx >> 9, k = idx & 511;
    int g = col >> 4, i = col & 15;
    size_t j = (size_t)(g * DD + c16 + i);
    float v = Wih1[j * DD + k] + Whh1[j * DD + k];
    W1L[((k >> 5) * 4 + ((k >> 3) & 3)) * 512 + col * 8 + (k & 7)] = (__bf16)v;
  }

  const int lane = tid & 63, w = tid >> 6;
  const int rm = lane & 15, lh = lane >> 4;
  const int arow  = r * 64 + w * 16 + rm;
  const int dcol  = c16 + rm;
  const int rbase = r * 64 + w * 16 + lh * 4;

  const __bf16* w0p = W0L + lh * 512 + rm * 8;
  const __bf16* w1p = W1L + lh * 512 + rm * 8;
  const __bf16* hb  = hbuf  + (size_t)arow * DD + lh * 8;
  const __bf16* h1b = h1buf + (size_t)arow * DD + lh * 8;

  // per-(group, wave) flag plane: 32 packed ints
  int* fplane = flags + (r * 4 + w) * 32;
  int* myflag = fplane + c;

  // resident biases (fragment layout)
  float preR[4][4], b1R[4];
#pragma unroll
  for (int g = 0; g < 4; ++g) {
    b1R[g] = bih1[g * DD + dcol] + bhh1[g * DD + dcol];
#pragma unroll
    for (int q = 0; q < 4; ++q)
      preR[g][q] = pre0[(size_t)(rbase + q) * G4 + g * DD + dcol];
  }
  const float dtv = dtp[0];
  float c1v[4] = {0.f,0.f,0.f,0.f};
  float c2v[4] = {0.f,0.f,0.f,0.f};
  float fz[4]  = {0.f,0.f,0.f,0.f};
  int budget = 1 << 22;

  // U(0) prefetch registers
  bf16x8 au0, au1, au2, au3;          // UBF path
  float4 u0,u1,u2,u3,u4,u5,u6,u7;     // raw path
  if constexpr (UBF) {
    const __bf16* ub = Ubf + (size_t)arow * UD + lh * 8;
    LDP16(au0, ub, 0)   LDP16(au1, ub, 64)
    LDP16(au2, ub, 128) LDP16(au3, ub, 192)
  } else {
    const float* ub = U + (size_t)arow * UD + lh * 8;
    LDP16(u0, ub, 0)   LDP16(u1, ub, 16)
    LDP16(u2, ub, 128) LDP16(u3, ub, 144)
    LDP16(u4, ub, 256) LDP16(u5, ub, 272)
    LDP16(u6, ub, 384) LDP16(u7, ub, 400)
  }

  __syncthreads();   // LDS weights ready (only block-sync in the kernel)

  for (int t = 0; t < TT; ++t) {
    // ============ layer 0: gates = [u*dt | h_prev] @ W0^T + pre0 ============
    {
      bf16x8 hh0,hh1,hh2,hh3,hh4,hh5,hh6,hh7,hh8,hh9,hhA,hhB,hhC,hhD,hhE,hhF;
      if (t > 0) {   // deferred Z stores ride this phase's drain
        float* Zp = Z + (size_t)(t - 1) * BB * DD + (size_t)rbase * DD + dcol;
#pragma unroll
        for (int q = 0; q < 4; ++q) Zp[(size_t)q * DD] = fz[q];
      }
      if (t > 0) wave_poll(fplane, 2 * t, lane, budget);   // h2(t-1) ready
      LOADH(hb)
      WAITV0
      bf16x8 au[4];
      if constexpr (UBF) {
        au[0] = au0; au[1] = au1; au[2] = au2; au[3] = au3;
      } else {
        au[0] = pack2(u0,u1,dtv); au[1] = pack2(u2,u3,dtv);
        au[2] = pack2(u4,u5,dtv); au[3] = pack2(u6,u7,dtv);
      }
      bf16x8 hA[16] = {hh0,hh1,hh2,hh3,hh4,hh5,hh6,hh7,
                       hh8,hh9,hhA,hhB,hhC,hhD,hhE,hhF};
      f32x4 acc[4] = {};
#pragma unroll
      for (int kc = 0; kc < 4; ++kc)
#pragma unroll
        for (int g = 0; g < 4; ++g) {
          bf16x8 b = *reinterpret_cast<const bf16x8*>(w0p + kc*2048 + g*128);
          acc[g] = mfma16(au[kc], b, acc[g]);
        }
#pragma unroll
      for (int kc = 0; kc < 16; ++kc)
#pragma unroll
        for (int g = 0; g < 4; ++g) {
          bf16x8 b = *reinterpret_cast<const bf16x8*>(w0p + (kc+4)*2048 + g*128);
          acc[g] = mfma16(hA[kc], b, acc[g]);
        }
#pragma unroll
      for (int q = 0; q < 4; ++q) {
        float gi = acc[0][q] + preR[0][q];
        float gf = acc[1][q] + preR[1][q];
        float gg = acc[2][q] + preR[2][q];
        float go = acc[3][q] + preR[3][q];
        float cn = sigm(gf) * c1v[q] + sigm(gi) * tanhfast(gg);
        c1v[q] = cn;
        float hn = sigm(go) * tanhfast(cn);
        st_ic(&h1buf[(size_t)(rbase + q) * DD + dcol], hn);
      }
      WAITV0
      if (lane == 0)
        __hip_atomic_store(myflag, 2 * t + 1, __ATOMIC_RELAXED, __HIP_MEMORY_SCOPE_AGENT);
    }
    // ============ layer 1: gates = h1 @ (Wih1+Whh1)^T + b1sum ============
    {
      bf16x8 hh0,hh1,hh2,hh3,hh4,hh5,hh6,hh7,hh8,hh9,hhA,hhB,hhC,hhD,hhE,hhF;
      wave_poll(fplane, 2 * t + 1, lane, budget);          // h1(t) ready
      LOADH(h1b)
      WAITV0
      bf16x8 hA[16] = {hh0,hh1,hh2,hh3,hh4,hh5,hh6,hh7,
                       hh8,hh9,hhA,hhB,hhC,hhD,hhE,hhF};
      f32x4 acc[4] = {};
#pragma unroll
      for (int kc = 0; kc < 16; ++kc)
#pragma unroll
        for (int g = 0; g < 4; ++g) {
          bf16x8 b = *reinterpret_cast<const bf16x8*>(w1p + kc*2048 + g*128);
          acc[g] = mfma16(hA[kc], b, acc[g]);
        }
#pragma unroll
      for (int q = 0; q < 4; ++q) {
        float gi = acc[0][q] + b1R[0];
        float gf = acc[1][q] + b1R[1];
        float gg = acc[2][q] + b1R[2];
        float go = acc[3][q] + b1R[3];
        float cn = sigm(gf) * c2v[q] + sigm(gi) * tanhfast(gg);
        c2v[q] = cn;
        float hn = sigm(go) * tanhfast(cn);
        fz[q] = hn;                                   // Z written next phase
        st_ic(&hbuf[(size_t)(rbase + q) * DD + dcol], hn);
      }
      if (t != TT - 1) {
        WAITV0
        if (lane == 0)
          __hip_atomic_store(myflag, 2 * t + 2, __ATOMIC_RELAXED, __HIP_MEMORY_SCOPE_AGENT);
        // prefetch U(t+1): latency hides under next poll
        if constexpr (UBF) {
          const __bf16* ub = Ubf + ((size_t)(t + 1) * BB + arow) * UD + lh * 8;
          LDP16(au0, ub, 0)   LDP16(au1, ub, 64)
          LDP16(au2, ub, 128) LDP16(au3, ub, 192)
        } else {
          const float* ub = U + ((size_t)(t + 1) * BB + arow) * UD + lh * 8;
          LDP16(u0, ub, 0)   LDP16(u1, ub, 16)
          LDP16(u2, ub, 128) LDP16(u3, ub, 144)
          LDP16(u4, ub, 256) LDP16(u5, ub, 272)
          LDP16(u6, ub, 384) LDP16(u7, ub, 400)
        }
      }
    }
  }
  // final Z slice
  {
    float* Zp = Z + (size_t)(TT - 1) * BB * DD + (size_t)rbase * DD + dcol;
#pragma unroll
    for (int q = 0; q < 4; ++q) Zp[(size_t)q * DD] = fz[q];
  }
}

// ---------------- batched output head: Y = [Z | dt*U] @ CD^T ----------------
__global__ __launch_bounds__(256) void y_kernel(
    const float* __restrict__ Z, const float* __restrict__ U,
    const float* __restrict__ dtp, const __bf16* __restrict__ CD,
    float* __restrict__ Y)
{
  int lane = threadIdx.x & 63, w = threadIdx.x >> 6;
  int rm = lane & 15;
  int rowbase = blockIdx.x * 128 + w * 32;
  int klane = (lane >> 4) * 8;
  float dtv = dtp[0];
  f32x4 acc[2][3] = {};
#pragma unroll
  for (int k0 = 0; k0 < KY; k0 += 32) {
    int k = k0 + klane;
    bf16x8 a[2];
#pragma unroll
    for (int rb = 0; rb < 2; ++rb) {
      int rr = rowbase + rb * 16 + rm;
      if (k0 < DD) a[rb] = cvt8(&Z[(size_t)rr * DD + k]);
      else         a[rb] = cvt8s(&U[(size_t)rr * UD + (k - DD)], dtv);
    }
#pragma unroll
    for (int cf = 0; cf < 3; ++cf) {
      bf16x8 b = *reinterpret_cast<const bf16x8*>(&CD[(size_t)(cf * 16 + rm) * KY + k]);
#pragma unroll
      for (int rb = 0; rb < 2; ++rb) acc[rb][cf] = mfma16(a[rb], b, acc[rb][cf]);
    }
  }
#pragma unroll
  for (int rb = 0; rb < 2; ++rb)
#pragma unroll
    for (int cf = 0; cf < 3; ++cf) {
      int n = cf * 16 + rm;
      if (n < NO)
#pragma unroll
        for (int q = 0; q < 4; ++q) {
          int rr = rowbase + rb * 16 + (lane >> 4) * 4 + q;
          Y[(size_t)rr * NO + n] = acc[rb][cf][q];
        }
    }
}

extern "C" void kernel_launch(void* const* d_in, const int* in_sizes, int n_in,
                              void* d_out, int out_size, void* d_ws, size_t ws_size,
                              hipStream_t stream) {
  const float* z_dyn    = (const float*)d_in[0];
  const float* z_static = (const float*)d_in[1];
  const float* dt       = (const float*)d_in[2];
  const float* U        = (const float*)d_in[3];
  const float* Wih0     = (const float*)d_in[4];
  const float* Whh0     = (const float*)d_in[5];
  const float* bih0     = (const float*)d_in[6];
  const float* bhh0     = (const float*)d_in[7];
  const float* Wih1     = (const float*)d_in[8];
  const float* Whh1     = (const float*)d_in[9];
  const float* bih1     = (const float*)d_in[10];
  const float* bhh1     = (const float*)d_in[11];
  const float* Cw       = (const float*)d_in[12];
  const float* Dw       = (const float*)d_in[13];

  float* out = (float*)d_out;
  float* Z = out;                                       // [TT, BB, DD]
  float* Y = out + (size_t)TT * BB * DD;                // [TT, BB, NO]

  char* p = (char*)d_ws;
  size_t used = 0;
  auto carve = [&](size_t bytes) {
    void* ret = (void*)p;
    size_t a = (bytes + 255) & ~(size_t)255;
    p += a; used += a;
    return ret;
  };
  __bf16* CD     = (__bf16*)carve((size_t)NY * KY * 2);
  float*  pre0   = (float*)carve((size_t)BB * G4 * 4);
  __bf16* hbuf   = (__bf16*)carve((size_t)BB * DD * 2);
  __bf16* h1buf  = (__bf16*)carve((size_t)BB * DD * 2);
  int*    flags  = (int*)carve((size_t)NFLAGS * 4);
  size_t ubytes  = (size_t)TT * BB * UD * 2;            // 16.78 MB
  bool useUbf = (ws_size >= used + ubytes + 256);
  __bf16* Ubf = useUbf ? (__bf16*)carve(ubytes) : nullptr;

  prep_kernel<<<1024, 256, 0, stream>>>(z_dyn, Cw, Dw, CD, hbuf, flags);
  pre0_kernel<<<dim3(8, 32), 256, 0, stream>>>(z_static, Wih0, bih0, bhh0, pre0);
  if (useUbf) {
    ucvt_kernel<<<(TT * BB * UD / 8 + 255) / 256, 256, 0, stream>>>(U, dt, Ubf);
    persist_kernel<true><<<256, 256, LDSB, stream>>>(
        U, Ubf, dt, Wih0, Whh0, Wih1, Whh1, bih1, bhh1, pre0,
        hbuf, h1buf, flags, Z);
  } else {
    persist_kernel<false><<<256, 256, LDSB, stream>>>(
        U, nullptr, dt, Wih0, Whh0, Wih1, Whh1, bih1, bhh1, pre0,
        hbuf, h1buf, flags, Z);
  }
  y_kernel<<<512, 256, 0, stream>>>(Z, U, dt, CD, Y);
}

// Round 9
// 1455.659 us; speedup vs baseline: 1.6155x; 1.6155x over previous
//
#include <hip/hip_runtime.h>

// Problem constants
#define BB   512
#define TT   128
#define DD   512
#define DS   256
#define UD   128
#define NO   40
#define G4   2048
#define KY   640
#define NY   48

#define NRG  8               // row groups (64 rows each)
#define NCS  32              // col slices (16 d-cols each)
// flags: (group, wave, col-slice) each in its OWN 64B line -> no line sharing
#define NFLAGI ((NRG*4*NCS)*16)     // ints (64 KB)
// frag-major LDS: W0 [20 kc][4 lh][64 col][8 e], W1 [16 kc][4][64][8]
#define LDS_W0  (640*64*2)          // 81920
#define LDS_W1  (512*64*2)          // 65536
#define LDSB    (LDS_W0 + LDS_W1)   // 147456

typedef __bf16 bf16x8 __attribute__((ext_vector_type(8)));
typedef float  f32x4  __attribute__((ext_vector_type(4)));

__device__ __forceinline__ f32x4 mfma16(bf16x8 a, bf16x8 b, f32x4 c) {
  return __builtin_amdgcn_mfma_f32_16x16x32_bf16(a, b, c, 0, 0, 0);
}
__device__ __forceinline__ float sigm(float x)     { return 1.0f / (1.0f + __expf(-x)); }
__device__ __forceinline__ float tanhfast(float x) { return 2.0f / (1.0f + __expf(-2.0f * x)) - 1.0f; }

__device__ __forceinline__ bf16x8 cvt8(const float* __restrict__ p) {
  const float4 u0 = *reinterpret_cast<const float4*>(p);
  const float4 u1 = *reinterpret_cast<const float4*>(p + 4);
  bf16x8 r;
  r[0]=(__bf16)u0.x; r[1]=(__bf16)u0.y; r[2]=(__bf16)u0.z; r[3]=(__bf16)u0.w;
  r[4]=(__bf16)u1.x; r[5]=(__bf16)u1.y; r[6]=(__bf16)u1.z; r[7]=(__bf16)u1.w;
  return r;
}
__device__ __forceinline__ bf16x8 cvt8s(const float* __restrict__ p, float s) {
  const float4 u0 = *reinterpret_cast<const float4*>(p);
  const float4 u1 = *reinterpret_cast<const float4*>(p + 4);
  bf16x8 r;
  r[0]=(__bf16)(u0.x*s); r[1]=(__bf16)(u0.y*s); r[2]=(__bf16)(u0.z*s); r[3]=(__bf16)(u0.w*s);
  r[4]=(__bf16)(u1.x*s); r[5]=(__bf16)(u1.y*s); r[6]=(__bf16)(u1.z*s); r[7]=(__bf16)(u1.w*s);
  return r;
}
__device__ __forceinline__ bf16x8 pack2(float4 a, float4 b, float s) {
  bf16x8 r;
  r[0]=(__bf16)(a.x*s); r[1]=(__bf16)(a.y*s); r[2]=(__bf16)(a.z*s); r[3]=(__bf16)(a.w*s);
  r[4]=(__bf16)(b.x*s); r[5]=(__bf16)(b.y*s); r[6]=(__bf16)(b.z*s); r[7]=(__bf16)(b.w*s);
  return r;
}

// ---- proven primitives (R2/R5 semantics): agent-scope comms only ----------
#define LDIC16(dst, base, IMM)                                              \
  asm volatile("global_load_dwordx4 %0, %1, off offset:" #IMM " sc0 sc1"    \
               : "=&v"(dst) : "v"(base));
#define LDP16(dst, base, IMM)                                               \
  asm volatile("global_load_dwordx4 %0, %1, off offset:" #IMM               \
               : "=&v"(dst) : "v"(base));
#define WAITV0                                                              \
  { asm volatile("s_waitcnt vmcnt(0)" ::: "memory");                        \
    __builtin_amdgcn_sched_barrier(0); }

#define LOADH(base)                                                         \
  LDIC16(hh0, base, 0)    LDIC16(hh1, base, 64)                             \
  LDIC16(hh2, base, 128)  LDIC16(hh3, base, 192)                            \
  LDIC16(hh4, base, 256)  LDIC16(hh5, base, 320)                            \
  LDIC16(hh6, base, 384)  LDIC16(hh7, base, 448)                            \
  LDIC16(hh8, base, 512)  LDIC16(hh9, base, 576)                            \
  LDIC16(hhA, base, 640)  LDIC16(hhB, base, 704)                            \
  LDIC16(hhC, base, 768)  LDIC16(hhD, base, 832)                            \
  LDIC16(hhE, base, 896)  LDIC16(hhF, base, 960)

// agent-scope bf16 store (R2/R5-proven)
__device__ __forceinline__ void st_ic(__bf16* p, float v) {
  __bf16 h = (__bf16)v;
  unsigned short us = __builtin_bit_cast(unsigned short, h);
  __hip_atomic_store((unsigned short*)p, us, __ATOMIC_RELAXED, __HIP_MEMORY_SCOPE_AGENT);
}

// wave-plane poll over SPREAD flags: lane i spins on line i (R5-proven pattern)
__device__ __forceinline__ void wave_poll(int* fplane, int ep, int lane, int& budget) {
  if (lane < 32) {
    const int* f = fplane + lane * 16;
    while (__hip_atomic_load(f, __ATOMIC_RELAXED, __HIP_MEMORY_SCOPE_AGENT) < ep) {
      if (--budget < 0) break;                 // hang guard
      __builtin_amdgcn_s_sleep(1);
    }
  }
  // lanes reconverge here; wave proceeds when all its pollers exited
}

// ---------------- one-time prep ----------------
__global__ __launch_bounds__(256) void prep_kernel(
    const float* __restrict__ z_dyn,
    const float* __restrict__ Cw, const float* __restrict__ Dw,
    __bf16* __restrict__ CD, __bf16* __restrict__ hbuf, int* __restrict__ flags)
{
  int idx = blockIdx.x * 256 + threadIdx.x;
  if (idx < NFLAGI) flags[idx] = 0;
  if (idx < NY * KY) {
    int o = idx / KY, k = idx - o * KY;
    float v = 0.f;
    if (o < NO) v = (k < DD) ? Cw[o * DD + k] : Dw[o * UD + (k - DD)];
    CD[idx] = (__bf16)v;
  }
  if (idx < BB * DD) hbuf[idx] = (__bf16)z_dyn[idx];
}

// ---------------- U * dt -> bf16, one pass ----------------
__global__ __launch_bounds__(256) void ucvt_kernel(
    const float* __restrict__ U, const float* __restrict__ dtp,
    __bf16* __restrict__ Ubf)
{
  float dtv = dtp[0];
  size_t i = ((size_t)blockIdx.x * 256 + threadIdx.x) * 8;
  float4 a = *reinterpret_cast<const float4*>(U + i);
  float4 b = *reinterpret_cast<const float4*>(U + i + 4);
  *reinterpret_cast<bf16x8*>(Ubf + i) = pack2(a, b, dtv);
}

// ---------------- pre0[b,j] = z_static @ Wih0[:,128:384]^T + bih0 + bhh0 ----
__global__ __launch_bounds__(256) void pre0_kernel(
    const float* __restrict__ z_static, const float* __restrict__ Wih0,
    const float* __restrict__ bih0, const float* __restrict__ bhh0,
    float* __restrict__ pre0)
{
  int lane = threadIdx.x & 63, w = threadIdx.x >> 6;
  int rm = lane & 15;
  int row = blockIdx.x * 64 + w * 16 + rm;
  int j0 = blockIdx.y * 64;
  int klane = (lane >> 4) * 8;
  f32x4 acc[4] = {};
  for (int k0 = 0; k0 < DS; k0 += 32) {
    int k = k0 + klane;
    bf16x8 a = cvt8(&z_static[row * DS + k]);
#pragma unroll
    for (int cf = 0; cf < 4; ++cf) {
      int j = j0 + cf * 16 + rm;
      bf16x8 b = cvt8(&Wih0[j * (UD + DS) + UD + k]);
      acc[cf] = mfma16(a, b, acc[cf]);
    }
  }
  int rbase = blockIdx.x * 64 + w * 16 + (lane >> 4) * 4;
#pragma unroll
  for (int cf = 0; cf < 4; ++cf) {
    int j = j0 + cf * 16 + rm;
    float bj = bih0[j] + bhh0[j];
#pragma unroll
    for (int q = 0; q < 4; ++q)
      pre0[(size_t)(rbase + q) * G4 + j] = acc[cf][q] + bj;
  }
}

// ---------------- persistent scan kernel ----------------
// 256 blocks x 256 threads, 1 block/CU. block (r=bid&7, c=bid>>3):
// rows [r*64,+64), d-cols [c*16,+16) x 4 gates. W0+W1 frag-major in LDS.
// Each wave w runs an INDEPENDENT 16-row stream; it syncs only with wave-w
// counterparts across the 32 col-slices via its own spread flag plane.
// No __syncthreads in the loop -> waves overlap each other's barrier stalls.
template <bool UBF>
__global__ __launch_bounds__(256, 1) void persist_kernel(
    const float* __restrict__ U, const __bf16* __restrict__ Ubf,
    const float* __restrict__ dtp,
    const float* __restrict__ Wih0, const float* __restrict__ Whh0,
    const float* __restrict__ Wih1, const float* __restrict__ Whh1,
    const float* __restrict__ bih1, const float* __restrict__ bhh1,
    const float* __restrict__ pre0,
    __bf16* __restrict__ hbuf, __bf16* __restrict__ h1buf,
    int* __restrict__ flags, float* __restrict__ Z)
{
  extern __shared__ __align__(16) char smem[];
  __bf16* W0L = (__bf16*)smem;
  __bf16* W1L = (__bf16*)(smem + LDS_W0);

  const int tid = threadIdx.x;
  const int r = blockIdx.x & 7, c = blockIdx.x >> 3;
  const int c16 = c * 16;

  // stage W0 frag-major: (col,k) -> [((k>>5)*4+((k>>3)&3))*512 + col*8 + (k&7)]
  for (int idx = tid; idx < 64 * 640; idx += 256) {
    int col = idx / 640, k = idx - col * 640;
    int g = col >> 4, i = col & 15;
    size_t j = (size_t)(g * DD + c16 + i);
    float v = (k < UD) ? Wih0[j * (UD + DS) + k] : Whh0[j * DD + (k - UD)];
    W0L[((k >> 5) * 4 + ((k >> 3) & 3)) * 512 + col * 8 + (k & 7)] = (__bf16)v;
  }
  // stage W1 = Wih1+Whh1 frag-major
  for (int idx = tid; idx < 64 * 512; idx += 256) {
    int col = idx >> 9, k = idx & 511;
    int g = col >> 4, i = col & 15;
    size_t j = (size_t)(g * DD + c16 + i);
    float v = Wih1[j * DD + k] + Whh1[j * DD + k];
    W1L[((k >> 5) * 4 + ((k >> 3) & 3)) * 512 + col * 8 + (k & 7)] = (__bf16)v;
  }

  const int lane = tid & 63, w = tid >> 6;
  const int rm = lane & 15, lh = lane >> 4;
  const int arow  = r * 64 + w * 16 + rm;
  const int dcol  = c16 + rm;
  const int rbase = r * 64 + w * 16 + lh * 4;

  const __bf16* w0p = W0L + lh * 512 + rm * 8;
  const __bf16* w1p = W1L + lh * 512 + rm * 8;
  const __bf16* hb  = hbuf  + (size_t)arow * DD + lh * 8;
  const __bf16* h1b = h1buf + (size_t)arow * DD + lh * 8;

  // per-(group, wave) SPREAD flag plane: 32 lines, 64B apart
  int* fplane = flags + (r * 4 + w) * (NCS * 16);
  int* myflag = fplane + c * 16;

  // resident biases (fragment layout)
  float preR[4][4], b1R[4];
#pragma unroll
  for (int g = 0; g < 4; ++g) {
    b1R[g] = bih1[g * DD + dcol] + bhh1[g * DD + dcol];
#pragma unroll
    for (int q = 0; q < 4; ++q)
      preR[g][q] = pre0[(size_t)(rbase + q) * G4 + g * DD + dcol];
  }
  const float dtv = dtp[0];
  float c1v[4] = {0.f,0.f,0.f,0.f};
  float c2v[4] = {0.f,0.f,0.f,0.f};
  float fz[4]  = {0.f,0.f,0.f,0.f};
  int budget = 1 << 22;

  // U(0) prefetch
  bf16x8 au0, au1, au2, au3;          // UBF path
  float4 u0,u1,u2,u3,u4,u5,u6,u7;     // raw path
  if constexpr (UBF) {
    const __bf16* ub = Ubf + (size_t)arow * UD + lh * 8;
    LDP16(au0, ub, 0)   LDP16(au1, ub, 64)
    LDP16(au2, ub, 128) LDP16(au3, ub, 192)
  } else {
    const float* ub = U + (size_t)arow * UD + lh * 8;
    LDP16(u0, ub, 0)   LDP16(u1, ub, 16)
    LDP16(u2, ub, 128) LDP16(u3, ub, 144)
    LDP16(u4, ub, 256) LDP16(u5, ub, 272)
    LDP16(u6, ub, 384) LDP16(u7, ub, 400)
  }

  __syncthreads();   // LDS weights ready (only block-sync in the kernel)
  WAITV0             // U(0) prefetch drained -> au safe in first L0

  for (int t = 0; t < TT; ++t) {
    // ===== layer 0: gates = [u*dt | h_prev] @ W0^T + pre0 =====
    {
      bf16x8 hh0,hh1,hh2,hh3,hh4,hh5,hh6,hh7,hh8,hh9,hhA,hhB,hhC,hhD,hhE,hhF;
      if (t > 0) {   // deferred Z stores ride this phase's drain
        float* Zp = Z + (size_t)(t - 1) * BB * DD + (size_t)rbase * DD + dcol;
#pragma unroll
        for (int q = 0; q < 4; ++q) Zp[(size_t)q * DD] = fz[q];
      }
      if (t > 0) wave_poll(fplane, 2 * t, lane, budget);   // h2(t-1) ready
      LOADH(hb)
      // U-part MFMAs overlap the in-flight h loads (au drained last phase)
      bf16x8 au[4];
      if constexpr (UBF) {
        au[0] = au0; au[1] = au1; au[2] = au2; au[3] = au3;
      } else {
        au[0] = pack2(u0,u1,dtv); au[1] = pack2(u2,u3,dtv);
        au[2] = pack2(u4,u5,dtv); au[3] = pack2(u6,u7,dtv);
      }
      f32x4 acc[4] = {};
#pragma unroll
      for (int kc = 0; kc < 4; ++kc)
#pragma unroll
        for (int g = 0; g < 4; ++g) {
          bf16x8 b = *reinterpret_cast<const bf16x8*>(w0p + kc*2048 + g*128);
          acc[g] = mfma16(au[kc], b, acc[g]);
        }
      WAITV0   // h loads (and Z stores) complete
      bf16x8 hA[16] = {hh0,hh1,hh2,hh3,hh4,hh5,hh6,hh7,
                       hh8,hh9,hhA,hhB,hhC,hhD,hhE,hhF};
#pragma unroll
      for (int kc = 0; kc < 16; ++kc)
#pragma unroll
        for (int g = 0; g < 4; ++g) {
          bf16x8 b = *reinterpret_cast<const bf16x8*>(w0p + (kc+4)*2048 + g*128);
          acc[g] = mfma16(hA[kc], b, acc[g]);
        }
#pragma unroll
      for (int q = 0; q < 4; ++q) {
        float gi = acc[0][q] + preR[0][q];
        float gf = acc[1][q] + preR[1][q];
        float gg = acc[2][q] + preR[2][q];
        float go = acc[3][q] + preR[3][q];
        float cn = sigm(gf) * c1v[q] + sigm(gi) * tanhfast(gg);
        c1v[q] = cn;
        float hn = sigm(go) * tanhfast(cn);
        st_ic(&h1buf[(size_t)(rbase + q) * DD + dcol], hn);
      }
      WAITV0
      if (lane == 0)
        __hip_atomic_store(myflag, 2 * t + 1, __ATOMIC_RELAXED, __HIP_MEMORY_SCOPE_AGENT);
    }
    // ===== layer 1: gates = h1 @ (Wih1+Whh1)^T + b1sum =====
    {
      bf16x8 hh0,hh1,hh2,hh3,hh4,hh5,hh6,hh7,hh8,hh9,hhA,hhB,hhC,hhD,hhE,hhF;
      wave_poll(fplane, 2 * t + 1, lane, budget);          // h1(t) ready
      LOADH(h1b)
      // U(t+1) prefetch issues with the h1 loads; drained by the WAITV0 below
      if (t != TT - 1) {
        if constexpr (UBF) {
          const __bf16* ub = Ubf + ((size_t)(t + 1) * BB + arow) * UD + lh * 8;
          LDP16(au0, ub, 0)   LDP16(au1, ub, 64)
          LDP16(au2, ub, 128) LDP16(au3, ub, 192)
        } else {
          const float* ub = U + ((size_t)(t + 1) * BB + arow) * UD + lh * 8;
          LDP16(u0, ub, 0)   LDP16(u1, ub, 16)
          LDP16(u2, ub, 128) LDP16(u3, ub, 144)
          LDP16(u4, ub, 256) LDP16(u5, ub, 272)
          LDP16(u6, ub, 384) LDP16(u7, ub, 400)
        }
      }
      WAITV0
      bf16x8 hA[16] = {hh0,hh1,hh2,hh3,hh4,hh5,hh6,hh7,
                       hh8,hh9,hhA,hhB,hhC,hhD,hhE,hhF};
      f32x4 acc[4] = {};
#pragma unroll
      for (int kc = 0; kc < 16; ++kc)
#pragma unroll
        for (int g = 0; g < 4; ++g) {
          bf16x8 b = *reinterpret_cast<const bf16x8*>(w1p + kc*2048 + g*128);
          acc[g] = mfma16(hA[kc], b, acc[g]);
        }
#pragma unroll
      for (int q = 0; q < 4; ++q) {
        float gi = acc[0][q] + b1R[0];
        float gf = acc[1][q] + b1R[1];
        float gg = acc[2][q] + b1R[2];
        float go = acc[3][q] + b1R[3];
        float cn = sigm(gf) * c2v[q] + sigm(gi) * tanhfast(gg);
        c2v[q] = cn;
        float hn = sigm(go) * tanhfast(cn);
        fz[q] = hn;                                   // Z written next phase
        st_ic(&hbuf[(size_t)(rbase + q) * DD + dcol], hn);
      }
      if (t != TT - 1) {
        WAITV0
        if (lane == 0)
          __hip_atomic_store(myflag, 2 * t + 2, __ATOMIC_RELAXED, __HIP_MEMORY_SCOPE_AGENT);
      }
    }
  }
  // final Z slice
  {
    float* Zp = Z + (size_t)(TT - 1) * BB * DD + (size_t)rbase * DD + dcol;
#pragma unroll
    for (int q = 0; q < 4; ++q) Zp[(size_t)q * DD] = fz[q];
  }
}

// ---------------- batched output head: Y = [Z | dt*U] @ CD^T ----------------
__global__ __launch_bounds__(256) void y_kernel(
    const float* __restrict__ Z, const float* __restrict__ U,
    const float* __restrict__ dtp, const __bf16* __restrict__ CD,
    float* __restrict__ Y)
{
  int lane = threadIdx.x & 63, w = threadIdx.x >> 6;
  int rm = lane & 15;
  int rowbase = blockIdx.x * 128 + w * 32;
  int klane = (lane >> 4) * 8;
  float dtv = dtp[0];
  f32x4 acc[2][3] = {};
#pragma unroll
  for (int k0 = 0; k0 < KY; k0 += 32) {
    int k = k0 + klane;
    bf16x8 a[2];
#pragma unroll
    for (int rb = 0; rb < 2; ++rb) {
      int rr = rowbase + rb * 16 + rm;
      if (k0 < DD) a[rb] = cvt8(&Z[(size_t)rr * DD + k]);
      else         a[rb] = cvt8s(&U[(size_t)rr * UD + (k - DD)], dtv);
    }
#pragma unroll
    for (int cf = 0; cf < 3; ++cf) {
      bf16x8 b = *reinterpret_cast<const bf16x8*>(&CD[(size_t)(cf * 16 + rm) * KY + k]);
#pragma unroll
      for (int rb = 0; rb < 2; ++rb) acc[rb][cf] = mfma16(a[rb], b, acc[rb][cf]);
    }
  }
#pragma unroll
  for (int rb = 0; rb < 2; ++rb)
#pragma unroll
    for (int cf = 0; cf < 3; ++cf) {
      int n = cf * 16 + rm;
      if (n < NO)
#pragma unroll
        for (int q = 0; q < 4; ++q) {
          int rr = rowbase + rb * 16 + (lane >> 4) * 4 + q;
          Y[(size_t)rr * NO + n] = acc[rb][cf][q];
        }
    }
}

extern "C" void kernel_launch(void* const* d_in, const int* in_sizes, int n_in,
                              void* d_out, int out_size, void* d_ws, size_t ws_size,
                              hipStream_t stream) {
  const float* z_dyn    = (const float*)d_in[0];
  const float* z_static = (const float*)d_in[1];
  const float* dt       = (const float*)d_in[2];
  const float* U        = (const float*)d_in[3];
  const float* Wih0     = (const float*)d_in[4];
  const float* Whh0     = (const float*)d_in[5];
  const float* bih0     = (const float*)d_in[6];
  const float* bhh0     = (const float*)d_in[7];
  const float* Wih1     = (const float*)d_in[8];
  const float* Whh1     = (const float*)d_in[9];
  const float* bih1     = (const float*)d_in[10];
  const float* bhh1     = (const float*)d_in[11];
  const float* Cw       = (const float*)d_in[12];
  const float* Dw       = (const float*)d_in[13];

  float* out = (float*)d_out;
  float* Z = out;                                       // [TT, BB, DD]
  float* Y = out + (size_t)TT * BB * DD;                // [TT, BB, NO]

  char* p = (char*)d_ws;
  size_t used = 0;
  auto carve = [&](size_t bytes) {
    void* ret = (void*)p;
    size_t a = (bytes + 255) & ~(size_t)255;
    p += a; used += a;
    return ret;
  };
  __bf16* CD     = (__bf16*)carve((size_t)NY * KY * 2);
  float*  pre0   = (float*)carve((size_t)BB * G4 * 4);
  __bf16* hbuf   = (__bf16*)carve((size_t)BB * DD * 2);
  __bf16* h1buf  = (__bf16*)carve((size_t)BB * DD * 2);
  int*    flags  = (int*)carve((size_t)NFLAGI * 4);
  size_t ubytes  = (size_t)TT * BB * UD * 2;            // 16.78 MB
  bool useUbf = (ws_size >= used + ubytes + 256);
  __bf16* Ubf = useUbf ? (__bf16*)carve(ubytes) : nullptr;

  prep_kernel<<<1024, 256, 0, stream>>>(z_dyn, Cw, Dw, CD, hbuf, flags);
  pre0_kernel<<<dim3(8, 32), 256, 0, stream>>>(z_static, Wih0, bih0, bhh0, pre0);
  if (useUbf) {
    ucvt_kernel<<<(TT * BB * UD / 8 + 255) / 256, 256, 0, stream>>>(U, dt, Ubf);
    persist_kernel<true><<<256, 256, LDSB, stream>>>(
        U, Ubf, dt, Wih0, Whh0, Wih1, Whh1, bih1, bhh1, pre0,
        hbuf, h1buf, flags, Z);
  } else {
    persist_kernel<false><<<256, 256, LDSB, stream>>>(
        U, nullptr, dt, Wih0, Whh0, Wih1, Whh1, bih1, bhh1, pre0,
        hbuf, h1buf, flags, Z);
  }
  y_kernel<<<512, 256, 0, stream>>>(Z, U, dt, CD, Y);
}